// Round 14
// baseline (776.761 us; speedup 1.0000x reference)
//
#include <hip/hip_runtime.h>

#define BB 4
#define CC 64
#define TT 800
#define FF 65
#define EE 8
#define CVV 16
#define HH 4

typedef __attribute__((ext_vector_type(8))) short short8;
typedef __attribute__((ext_vector_type(4))) float f32x4;

#define OT_SLAB (800 * 65 * 16)   // shorts per (b,h) slab of Ot (no f-pad)

__device__ __forceinline__ float bf2f(unsigned short u) {
  unsigned v = ((unsigned)u) << 16;
  return __builtin_bit_cast(float, v);
}
__device__ __forceinline__ unsigned short f2bf(float f) {
  unsigned u = __builtin_bit_cast(unsigned, f);
  unsigned r = (u + 0x7fffu + ((u >> 16) & 1u)) >> 16;
  return (unsigned short)r;
}

// direct global->LDS async copy, 16B per lane; lds dst must be wave-uniform
__device__ __forceinline__ void gll16(const void* g, void* l) {
  __builtin_amdgcn_global_load_lds(
      (const __attribute__((address_space(1))) void*)g,
      (__attribute__((address_space(3))) void*)l, 16, 0, 0);
}

// ---------------- K0: x = concat(pos, neg) + seg -> X fp32 ----------------
__global__ __launch_bounds__(256) void buildx_kernel(
    const float* __restrict__ pos, const float* __restrict__ neg,
    const float* __restrict__ seg, float* __restrict__ X)
{
  size_t i = (size_t)blockIdx.x * 256 + threadIdx.x;
  const size_t total = (size_t)BB * CC * TT * FF;
  if (i >= total) return;
  int f = (int)(i % FF);
  size_t r = i / FF;
  int t = (int)(r % TT);
  size_t r2 = r / TT;
  int c = (int)(r2 % CC);
  int b = (int)(r2 / CC);
  float v; int si;
  if (t < 400) { v = pos[(((size_t)b * CC + c) * 400 + t) * FF + f]; si = 0; }
  else         { v = neg[(((size_t)b * CC + c) * 400 + (t - 400)) * FF + f]; si = 1; }
  X[i] = v + seg[(size_t)si * CC * FF + c * FF + f];
}

// ---------------- Xt0: X[b][c][pos] fp32 -> Xt[b][pos][c] bf16 ----------------
__global__ __launch_bounds__(256) void xt0_kernel(
    const float* __restrict__ X, unsigned short* __restrict__ Xt)
{
  __shared__ unsigned short tile[64][66];
  int b = blockIdx.y;
  int p0 = blockIdx.x * 64;
  int tid = threadIdx.x;
#pragma unroll
  for (int it = 0; it < 16; ++it) {
    int idx = it * 256 + tid;
    int c = idx >> 6, pp = idx & 63;
    int ps = p0 + pp;
    float v = (ps < 52000) ? X[((size_t)b * 64 + c) * 52000 + ps] : 0.f;
    tile[pp][c] = f2bf(v);
  }
  __syncthreads();
#pragma unroll
  for (int it = 0; it < 16; ++it) {
    int idx = it * 256 + tid;
    int pp = idx >> 6, c = idx & 63;
    int ps = p0 + pp;
    Xt[((size_t)b * 52032 + ps) * 64 + c] = tile[pp][c];
  }
}

// ---------------- K1: standalone QKV projection (layer 0 only) ----------------
__global__ __launch_bounds__(512) void qkv_gemm_kernel(
    const unsigned short* __restrict__ Xt,
    const float* __restrict__ Qw, const float* __restrict__ Qb, const float* __restrict__ Qa,
    const float* __restrict__ Qg, const float* __restrict__ Qbe,
    const float* __restrict__ Kw, const float* __restrict__ Kbi, const float* __restrict__ Ka,
    const float* __restrict__ Kg, const float* __restrict__ Kbe,
    const float* __restrict__ Vw, const float* __restrict__ Vb, const float* __restrict__ Va,
    const float* __restrict__ Vg, const float* __restrict__ Vbe,
    unsigned short* __restrict__ Qo, unsigned short* __restrict__ Ko,
    unsigned short* __restrict__ Vo, int li)
{
  __shared__ __align__(16) unsigned short lds[26624];
  unsigned short* lA = lds;

  int wg = (blockIdx.x & 7) * 100 + (blockIdx.x >> 3);
  int b = wg & 3, tb = wg >> 2;
  int tid = threadIdx.x;
  int lane = tid & 63, wid = tid >> 6;
  int tp = wid >> 2;
  int ws2 = wid & 3;
  int t0 = tb * 4 + tp * 2;
  unsigned short* lB = lds + 8192 + tp * 9216;

  // zero K-dim pad cols [520,576) of Q/K rows t=4tb..4tb+3, all heads (clear poison)
  for (int i = tid; i < 896; i += 512) {
    int u = i / 28, c = i - u * 28;
    int h = u >> 3, arr = (u >> 2) & 1, tt = u & 3;
    unsigned short* bp = arr ? Ko : Qo;
    unsigned* dst = (unsigned*)(bp + ((size_t)(h * 4 + b) * 896 + tb * 4 + tt) * 576) + 260 + c;
    *dst = 0u;
  }

  // stage B (async): Xt rows via global_load_lds, pre-swizzled source
  const unsigned short* xb = Xt + ((size_t)b * 52032 + tb * 260) * 64;
  const int srow = lane >> 3;
  const int gc8s = (lane & 7) ^ srow;
#pragma unroll
  for (int it = 0; it < 5; ++it) {
    int s = it * 8 + wid;
    if (s < 36) {
      int pair = (s >= 18) ? 1 : 0;
      int r0 = (s - pair * 18) * 8;
      int row = r0 + srow;
      gll16(&xb[(size_t)(pair * 130 + row) * 64 + gc8s * 8],
            lds + 8192 + pair * 9216 + r0 * 64);
    }
  }

  // stage A: weights fp32 -> bf16
  const float* Wq = Qw + (size_t)li * 2048;
  const float* Wk = Kw + (size_t)li * 2048;
  const float* Wv = Vw + (size_t)li * 4096;
#pragma unroll
  for (int q = 0; q < 2; ++q) {
    int chunk = q * 512 + tid;
    int row = chunk >> 3, c8 = chunk & 7;
    const float* src = (row < 32) ? (Wq + row * 64)
                     : (row < 64) ? (Wk + (row - 32) * 64)
                                  : (Wv + (row - 64) * 64);
    float4 f0 = *(const float4*)(src + c8 * 8);
    float4 f1 = *(const float4*)(src + c8 * 8 + 4);
    uint4 u;
    u.x = (unsigned)f2bf(f0.x) | ((unsigned)f2bf(f0.y) << 16);
    u.y = (unsigned)f2bf(f0.z) | ((unsigned)f2bf(f0.w) << 16);
    u.z = (unsigned)f2bf(f1.x) | ((unsigned)f2bf(f1.y) << 16);
    u.w = (unsigned)f2bf(f1.z) | ((unsigned)f2bf(f1.w) << 16);
    *(uint4*)&lA[row * 64 + ((c8 * 8) ^ ((row & 7) << 3))] = u;
  }
  __syncthreads();

  f32x4 acc[2][9];
#pragma unroll
  for (int i = 0; i < 2; ++i)
#pragma unroll
    for (int j = 0; j < 9; ++j) acc[i][j] = {0.f, 0.f, 0.f, 0.f};
  const int fr = lane & 15, fk = lane >> 4;
  const int swz = (lane & 7) << 3;
#pragma unroll
  for (int kk = 0; kk < 2; ++kk) {
    int ko = (kk * 32 + fk * 8) ^ swz;
    short8 a0 = *(const short8*)&lA[(ws2 * 32 + fr) * 64 + ko];
    short8 a1 = *(const short8*)&lA[(ws2 * 32 + 16 + fr) * 64 + ko];
#pragma unroll
    for (int nf = 0; nf < 9; ++nf) {
      short8 bfr = *(const short8*)&lB[(nf * 16 + fr) * 64 + ko];
      acc[0][nf] = __builtin_amdgcn_mfma_f32_16x16x32_bf16(a0, bfr, acc[0][nf], 0, 0, 0);
      acc[1][nf] = __builtin_amdgcn_mfma_f32_16x16x32_bf16(a1, bfr, acc[1][nf], 0, 0, 0);
    }
  }
  __syncthreads();

  // stage gamma/beta interleaved bf16
  for (int it = 0; it < 17; ++it) {
    int i = it * 512 + tid;
    if (i < 8320) {
      int row = i / 65;
      float g, be;
      if (i < 2080)      { g = Qg[li * 2080 + i];          be = Qbe[li * 2080 + i]; }
      else if (i < 4160) { g = Kg[li * 2080 + (i - 2080)]; be = Kbe[li * 2080 + (i - 2080)]; }
      else               { g = Vg[li * 4160 + (i - 4160)]; be = Vbe[li * 4160 + (i - 4160)]; }
      unsigned pk = (unsigned)f2bf(g) | ((unsigned)f2bf(be) << 16);
      *(unsigned*)&lds[(i + row) * 2] = pk;
    }
  }

  int r4 = (lane >> 4) * 4;
  float mu0_[2], rs0_[2], mu1_[2], rs1_[2];
#pragma unroll
  for (int mf2 = 0; mf2 < 2; ++mf2) {
    int rbase = ws2 * 32 + mf2 * 16 + r4;
    float bias[4], alpha;
    if (rbase < 32) {
      alpha = Qa[li * 4 + (rbase >> 3)];
#pragma unroll
      for (int j = 0; j < 4; ++j) bias[j] = Qb[li * 32 + rbase + j];
    } else if (rbase < 64) {
      alpha = Ka[li * 4 + ((rbase - 32) >> 3)];
#pragma unroll
      for (int j = 0; j < 4; ++j) bias[j] = Kbi[li * 32 + rbase - 32 + j];
    } else {
      alpha = Va[li * 4 + ((rbase - 64) >> 4)];
#pragma unroll
      for (int j = 0; j < 4; ++j) bias[j] = Vb[li * 64 + rbase - 64 + j];
    }
    float s0 = 0.f, ss0 = 0.f, s1 = 0.f, ss1 = 0.f;
#pragma unroll
    for (int nf = 0; nf < 9; ++nf) {
      int col = nf * 16 + fr;
#pragma unroll
      for (int j = 0; j < 4; ++j) {
        float v = acc[mf2][nf][j] + bias[j];
        v = v >= 0.f ? v : alpha * v;
        acc[mf2][nf][j] = v;
        if (col < 65) { s0 += v; ss0 += v * v; }
        else if (col < 130) { s1 += v; ss1 += v * v; }
      }
    }
    if (ws2 < 2) {
#pragma unroll
      for (int off = 1; off < 32; off <<= 1) {
        s0 += __shfl_xor(s0, off); ss0 += __shfl_xor(ss0, off);
        s1 += __shfl_xor(s1, off); ss1 += __shfl_xor(ss1, off);
      }
    } else {
#pragma unroll
      for (int off = 1; off < 64; off <<= 1) {
        s0 += __shfl_xor(s0, off); ss0 += __shfl_xor(ss0, off);
        s1 += __shfl_xor(s1, off); ss1 += __shfl_xor(ss1, off);
      }
    }
    float invn = (ws2 < 2) ? (1.f / 520.f) : (1.f / 1040.f);
    float m0v = s0 * invn, m1v = s1 * invn;
    mu0_[mf2] = m0v; rs0_[mf2] = rsqrtf(ss0 * invn - m0v * m0v + 1e-5f);
    mu1_[mf2] = m1v; rs1_[mf2] = rsqrtf(ss1 * invn - m1v * m1v + 1e-5f);
  }
  __syncthreads();

#pragma unroll
  for (int mf2 = 0; mf2 < 2; ++mf2) {
#pragma unroll
    for (int j = 0; j < 4; ++j) {
      int row = ws2 * 32 + mf2 * 16 + r4 + j;
      unsigned short* dst; int LD;
      if (row < 32) {
        dst = Qo + ((size_t)((row >> 3) * 4 + b) * 896 + t0) * 576 + (row & 7) * 65; LD = 576;
      } else if (row < 64) {
        int rk = row - 32;
        dst = Ko + ((size_t)((rk >> 3) * 4 + b) * 896 + t0) * 576 + (rk & 7) * 65; LD = 576;
      } else {
        int rv = row - 64;
        dst = Vo + ((size_t)((rv >> 4) * 4 + b) * 800 + t0) * 1040 + (rv & 15) * 65; LD = 1040;
      }
      int grow = row * 132;
#pragma unroll
      for (int nf = 0; nf < 9; ++nf) {
        int col = nf * 16 + fr;
        if (col >= 130) continue;
        int half = (col >= 65) ? 1 : 0;
        int f = col - half * 65;
        unsigned pk = *(const unsigned*)&lds[grow + f * 2];
        float g = bf2f((unsigned short)(pk & 0xffff));
        float be = bf2f((unsigned short)(pk >> 16));
        float mu = half ? mu1_[mf2] : mu0_[mf2];
        float rs = half ? rs1_[mf2] : rs0_[mf2];
        dst[(size_t)half * LD + f] = f2bf((acc[mf2][nf][j] - mu) * rs * g + be);
      }
    }
  }
}

// ---------------- V transpose ----------------
__global__ __launch_bounds__(256) void vtrans_kernel(
    const unsigned short* __restrict__ V, unsigned short* __restrict__ Vt)
{
  __shared__ unsigned short tile[64][66];
  int z = blockIdx.z;
  const unsigned short* Vp = V + (size_t)z * 800 * 1040;
  unsigned short* Vtp = Vt + (size_t)z * 1152 * 832;
  int t0 = blockIdx.x * 64, n0 = blockIdx.y * 64;
  int tid = threadIdx.x;
#pragma unroll
  for (int it = 0; it < 16; ++it) {
    int idx = it * 256 + tid;
    int r = idx >> 6, c = idx & 63;
    int t = t0 + r, n = n0 + c;
    tile[r][c] = (t < 800 && n < 1040) ? Vp[(size_t)t * 1040 + n] : (unsigned short)0;
  }
  __syncthreads();
#pragma unroll
  for (int it = 0; it < 16; ++it) {
    int idx = it * 256 + tid;
    int r = idx >> 6, c = idx & 63;
    int n = n0 + r;
    if (n < 1040) {
      int cv = n / 65, f5 = n - cv * 65;
      Vtp[(size_t)(f5 * 16 + cv) * 832 + t0 + c] = tile[c][r];
    }
  }
}

// ---------------- shared MFMA GEMM body ----------------
template <int LDA, int LDB, int KSTEPS>
__device__ __forceinline__ void gemm128(
    const unsigned short* __restrict__ Ag, const unsigned short* __restrict__ Bg,
    int m0, int n0, unsigned short* lA, unsigned short* lB, f32x4 acc[4][4])
{
  const int tid = threadIdx.x;
  const int lane = tid & 63;
  const int wid = tid >> 6;
  const int wm = wid >> 1, wn = wid & 1;

  const int fr = lane & 15, fk = lane >> 4;
  const int swz = (lane & 7) << 3;
  const int srow = lane >> 3;
  const int gc8 = (lane & 7) ^ srow;
  int aoff[4][2], boff[4][2];
#pragma unroll
  for (int mf = 0; mf < 4; ++mf)
#pragma unroll
    for (int kk = 0; kk < 2; ++kk) {
      aoff[mf][kk] = (wm * 64 + mf * 16 + fr) * 64 + ((kk * 32 + fk * 8) ^ swz);
      boff[mf][kk] = (wn * 64 + mf * 16 + fr) * 64 + ((kk * 32 + fk * 8) ^ swz);
    }

  const unsigned short* gA = Ag + (size_t)m0 * LDA;
  const unsigned short* gB = Bg + (size_t)n0 * LDB;

  for (int ks = 0; ks < KSTEPS; ++ks) {
    int k0 = ks * 64;
    __syncthreads();
#pragma unroll
    for (int i = 0; i < 4; ++i) {
      int r0 = wid * 32 + i * 8;
      gll16(&gA[(size_t)(r0 + srow) * LDA + k0 + gc8 * 8], &lA[r0 * 64]);
      gll16(&gB[(size_t)(r0 + srow) * LDB + k0 + gc8 * 8], &lB[r0 * 64]);
    }
    __syncthreads();
#pragma unroll
    for (int kk = 0; kk < 2; ++kk) {
      short8 a[4], b[4];
#pragma unroll
      for (int i = 0; i < 4; ++i) {
        a[i] = *(const short8*)&lA[aoff[i][kk]];
        b[i] = *(const short8*)&lB[boff[i][kk]];
      }
#pragma unroll
      for (int i = 0; i < 4; ++i)
#pragma unroll
        for (int j = 0; j < 4; ++j)
          acc[i][j] = __builtin_amdgcn_mfma_f32_16x16x32_bf16(a[i], b[j], acc[i][j], 0, 0, 0);
    }
  }
}

// ---------------- K2: S = Q @ K^T * scale -> bf16 scores ----------------
__global__ __launch_bounds__(256) void qk_mfma_kernel(
    const unsigned short* __restrict__ Q, const unsigned short* __restrict__ K,
    unsigned short* __restrict__ SP)
{
  __shared__ __align__(16) unsigned short lA[128 * 64];
  __shared__ __align__(16) unsigned short lB[128 * 64];
  int wg = (blockIdx.x & 7) * 98 + (blockIdx.x >> 3);
  int z = wg / 49, r = wg % 49;
  int nt = r / 7, mt = r % 7;
  const unsigned short* Ag = Q + (size_t)z * 896 * 576;
  const unsigned short* Bg = K + (size_t)z * 896 * 576;
  int m0 = mt * 128, n0 = nt * 128;
  f32x4 acc[4][4];
#pragma unroll
  for (int i = 0; i < 4; ++i)
#pragma unroll
    for (int j = 0; j < 4; ++j) acc[i][j] = {0.f, 0.f, 0.f, 0.f};
  gemm128<576, 576, 9>(Ag, Bg, m0, n0, lA, lB, acc);
  const int lane = threadIdx.x & 63, wid = threadIdx.x >> 6;
  const int wm = wid >> 1, wn = wid & 1;
  unsigned short* Sp = SP + (size_t)z * 896 * 832;
  const float scale = 0.04385290096535146f;   // 1/sqrt(520)
#pragma unroll
  for (int mf = 0; mf < 4; ++mf)
#pragma unroll
    for (int nf = 0; nf < 4; ++nf) {
      int n = n0 + wn * 64 + nf * 16 + (lane & 15);
      if (n >= 800) continue;
#pragma unroll
      for (int j = 0; j < 4; ++j) {
        int m = m0 + wm * 64 + mf * 16 + (lane >> 4) * 4 + j;
        if (m < 800) Sp[(size_t)m * 832 + n] = f2bf(acc[mf][nf][j] * scale);
      }
    }
}

// ---------------- K3: row softmax, one row per wave ----------------
__global__ __launch_bounds__(256) void softmax_bf16_kernel(unsigned short* __restrict__ SP)
{
  int wid = threadIdx.x >> 6, lane = threadIdx.x & 63;
  int row = blockIdx.x * 4 + wid;
  int z = row / 800, r = row - z * 800;
  unsigned short* p = SP + (size_t)z * 896 * 832 + (size_t)r * 832;
  float v[13];
  float mx = -1e30f;
#pragma unroll
  for (int i = 0; i < 13; ++i) {
    int col = i * 64 + lane;
    float x = (col < 800) ? bf2f(p[col]) : -1e30f;
    v[i] = x;
    mx = fmaxf(mx, x);
  }
#pragma unroll
  for (int off = 32; off; off >>= 1) mx = fmaxf(mx, __shfl_xor(mx, off));
  float s = 0.f;
#pragma unroll
  for (int i = 0; i < 13; ++i) { v[i] = __expf(v[i] - mx); s += v[i]; }
#pragma unroll
  for (int off = 32; off; off >>= 1) s += __shfl_xor(s, off);
  float inv = 1.0f / s;
#pragma unroll
  for (int i = 0; i < 13; ++i) {
    int col = i * 64 + lane;
    if (col < 832) p[col] = f2bf(v[i] * inv);
  }
}

// ---------------- K4: O = P @ Vt^T -> Ot[b][h][t][f 65][cv] bf16 ----------------
__global__ __launch_bounds__(256) void pv_mfma_kernel(
    const unsigned short* __restrict__ SP, const unsigned short* __restrict__ Vt,
    unsigned short* __restrict__ Ot)
{
  __shared__ __align__(16) unsigned short lA[128 * 64];
  __shared__ __align__(16) unsigned short lB[128 * 64];
  int wg = (blockIdx.x & 7) * 126 + (blockIdx.x >> 3);
  int z = wg / 63, r = wg % 63;
  int nt = r / 7, mt = r % 7;
  const unsigned short* Ag = SP + (size_t)z * 896 * 832;
  const unsigned short* Bg = Vt + (size_t)z * 1152 * 832;
  int m0 = mt * 128, n0 = nt * 128;
  f32x4 acc[4][4];
#pragma unroll
  for (int i = 0; i < 4; ++i)
#pragma unroll
    for (int j = 0; j < 4; ++j) acc[i][j] = {0.f, 0.f, 0.f, 0.f};
  gemm128<832, 832, 13>(Ag, Bg, m0, n0, lA, lB, acc);
  const int lane = threadIdx.x & 63, wid = threadIdx.x >> 6;
  const int wm = wid >> 1, wn = wid & 1;
  int h = z >> 2, bb = z & 3;
  unsigned short* Op = Ot + (size_t)(bb * 4 + h) * OT_SLAB;
#pragma unroll
  for (int mf = 0; mf < 4; ++mf)
#pragma unroll
    for (int nf = 0; nf < 4; ++nf) {
      int n = n0 + wn * 64 + nf * 16 + (lane & 15);
      if (n >= 1040) continue;
      int f5 = n >> 4, cv = n & 15;
#pragma unroll
      for (int j = 0; j < 4; ++j) {
        int m = m0 + wm * 64 + mf * 16 + (lane >> 4) * 4 + j;
        if (m < 800) Op[((size_t)m * 65 + f5) * 16 + cv] = f2bf(acc[mf][nf][j]);
      }
    }
}

// ---------------- K5a: FUSED pproj(li) + qkv(li+1), li in 0..2 ----------------
__global__ __launch_bounds__(512) void fused_pproj_qkv_kernel(
    const unsigned short* __restrict__ Ot,
    const float* __restrict__ Pw, const float* __restrict__ Pb,
    const float* __restrict__ Pa, const float* __restrict__ Pg, const float* __restrict__ Pbe,
    const float* __restrict__ X,
    const float* __restrict__ Qw, const float* __restrict__ Qb, const float* __restrict__ Qa,
    const float* __restrict__ Qg, const float* __restrict__ Qbe,
    const float* __restrict__ Kw, const float* __restrict__ Kbi, const float* __restrict__ Ka,
    const float* __restrict__ Kg, const float* __restrict__ Kbe,
    const float* __restrict__ Vw, const float* __restrict__ Vb, const float* __restrict__ Va,
    const float* __restrict__ Vg, const float* __restrict__ Vbe,
    unsigned short* __restrict__ Qo, unsigned short* __restrict__ Ko,
    unsigned short* __restrict__ Vo, int li)
{
  // [0,4096): sA (Pw)  | [4096,22528): sB0/sB1 -> later Y panels
  // [22528,30720): lA2 (QKV weights)  | gamma/beta table [0,16896) after phase2
  __shared__ __align__(16) unsigned short lds[30720];
  __shared__ float redbuf[8][4];
  unsigned short* sA = lds;
  unsigned short* lA2 = lds + 22528;
  const int lq = li + 1;

  int wg = (blockIdx.x & 7) * 100 + (blockIdx.x >> 3);
  int b = wg & 3, tb = wg >> 2;
  int tid = threadIdx.x, lane = tid & 63, wid = tid >> 6;
  int tp = wid >> 2;
  int ws = wid & 3;
  unsigned short* sB = sA + 4096 + tp * 9216;

  // zero K-dim pad cols [520,576) of Q/K rows t=4tb..4tb+3 (layer lq outputs)
  for (int i = tid; i < 896; i += 512) {
    int u = i / 28, c = i - u * 28;
    int h = u >> 3, arr = (u >> 2) & 1, tt = u & 3;
    unsigned short* bp = arr ? Ko : Qo;
    unsigned* dst = (unsigned*)(bp + ((size_t)(h * 4 + b) * 896 + tb * 4 + tt) * 576) + 260 + c;
    *dst = 0u;
  }

  // stage sB both pairs: assemble [row(130 pos)][c=h*16+cv] from Ot [b][h][t][65][16]
  const unsigned short* ob = Ot + (size_t)b * 4 * OT_SLAB;
#pragma unroll
  for (int q = 0; q < 5; ++q) {
    int chunk = q * 512 + tid;
    if (chunk < 2304) {
      int pair = (chunk >= 1152) ? 1 : 0;
      int ch = chunk - pair * 1152;
      int row = ch >> 3, c8 = ch & 7;
      int half = (row >= 65) ? 1 : 0;
      int f = row - half * 65;
      int tt = tb * 4 + pair * 2 + half;
      uint4 u = *(const uint4*)&ob[(size_t)(c8 >> 1) * OT_SLAB +
                                   ((size_t)tt * 65 + f) * 16 + (c8 & 1) * 8];
      unsigned short* sbp = sA + 4096 + pair * 9216;
      *(uint4*)&sbp[row * 64 + ((c8 * 8) ^ ((row & 7) << 3))] = u;
    }
  }
  // stage sA: Pw fp32 -> bf16
  const float* pw = Pw + (size_t)li * 4096;
  {
    int row = tid >> 3, c8 = tid & 7;
    float4 f0 = *(const float4*)(pw + row * 64 + c8 * 8);
    float4 f1 = *(const float4*)(pw + row * 64 + c8 * 8 + 4);
    uint4 u;
    u.x = (unsigned)f2bf(f0.x) | ((unsigned)f2bf(f0.y) << 16);
    u.y = (unsigned)f2bf(f0.z) | ((unsigned)f2bf(f0.w) << 16);
    u.z = (unsigned)f2bf(f1.x) | ((unsigned)f2bf(f1.y) << 16);
    u.w = (unsigned)f2bf(f1.z) | ((unsigned)f2bf(f1.w) << 16);
    *(uint4*)&sA[row * 64 + ((c8 * 8) ^ ((row & 7) << 3))] = u;
  }
  // stage lA2: QKV weights (layer lq) fp32 -> bf16
  const float* Wq = Qw + (size_t)lq * 2048;
  const float* Wk = Kw + (size_t)lq * 2048;
  const float* Wv = Vw + (size_t)lq * 4096;
#pragma unroll
  for (int q = 0; q < 2; ++q) {
    int chunk = q * 512 + tid;
    int row = chunk >> 3, c8 = chunk & 7;
    const float* src = (row < 32) ? (Wq + row * 64)
                     : (row < 64) ? (Wk + (row - 32) * 64)
                                  : (Wv + (row - 64) * 64);
    float4 f0 = *(const float4*)(src + c8 * 8);
    float4 f1 = *(const float4*)(src + c8 * 8 + 4);
    uint4 u;
    u.x = (unsigned)f2bf(f0.x) | ((unsigned)f2bf(f0.y) << 16);
    u.y = (unsigned)f2bf(f0.z) | ((unsigned)f2bf(f0.w) << 16);
    u.z = (unsigned)f2bf(f1.x) | ((unsigned)f2bf(f1.y) << 16);
    u.w = (unsigned)f2bf(f1.z) | ((unsigned)f2bf(f1.w) << 16);
    *(uint4*)&lA2[row * 64 + ((c8 * 8) ^ ((row & 7) << 3))] = u;
  }
  __syncthreads();                             // B0

  // phase-1 MFMA: Y = Pw @ Ot^T
  f32x4 acc[9];
#pragma unroll
  for (int j = 0; j < 9; ++j) acc[j] = {0.f, 0.f, 0.f, 0.f};
  const int fr = lane & 15, fk = lane >> 4;
  const int swz = (lane & 7) << 3;
#pragma unroll
  for (int kk = 0; kk < 2; ++kk) {
    int ko = (kk * 32 + fk * 8) ^ swz;
    short8 a = *(const short8*)&sA[(ws * 16 + fr) * 64 + ko];
#pragma unroll
    for (int nf = 0; nf < 9; ++nf) {
      short8 bb2 = *(const short8*)&sB[(nf * 16 + fr) * 64 + ko];
      acc[nf] = __builtin_amdgcn_mfma_f32_16x16x32_bf16(a, bb2, acc[nf], 0, 0, 0);
    }
  }

  // bias + PReLU + LN stats (groups: (pair, t-half), 64x65)
  float alpha = Pa[li];
  int rbase = ws * 16 + (lane >> 4) * 4;
  float bias[4];
#pragma unroll
  for (int j = 0; j < 4; ++j) bias[j] = Pb[li * 64 + rbase + j];
  float s0 = 0.f, ss0 = 0.f, s1 = 0.f, ss1 = 0.f;
#pragma unroll
  for (int nf = 0; nf < 9; ++nf) {
    int col = nf * 16 + fr;
#pragma unroll
    for (int j = 0; j < 4; ++j) {
      float v = acc[nf][j] + bias[j];
      v = v >= 0.f ? v : alpha * v;
      acc[nf][j] = v;
      if (col < 65) { s0 += v; ss0 += v * v; }
      else if (col < 130) { s1 += v; ss1 += v * v; }
    }
  }
#pragma unroll
  for (int off = 32; off; off >>= 1) {
    s0 += __shfl_xor(s0, off); ss0 += __shfl_xor(ss0, off);
    s1 += __shfl_xor(s1, off); ss1 += __shfl_xor(ss1, off);
  }
  if (lane == 0) {
    redbuf[wid][0] = s0; redbuf[wid][1] = ss0;
    redbuf[wid][2] = s1; redbuf[wid][3] = ss1;
  }
  __syncthreads();                             // B1 (sB reads also complete)
  int rb0 = tp * 4;
  float S0 = redbuf[rb0][0] + redbuf[rb0+1][0] + redbuf[rb0+2][0] + redbuf[rb0+3][0];
  float SS0 = redbuf[rb0][1] + redbuf[rb0+1][1] + redbuf[rb0+2][1] + redbuf[rb0+3][1];
  float S1 = redbuf[rb0][2] + redbuf[rb0+1][2] + redbuf[rb0+2][2] + redbuf[rb0+3][2];
  float SS1 = redbuf[rb0][3] + redbuf[rb0+1][3] + redbuf[rb0+2][3] + redbuf[rb0+3][3];
  const float invn = 1.f / 4160.f;
  float mu0 = S0 * invn, rs0 = rsqrtf(SS0 * invn - mu0 * mu0 + 1e-5f);
  float mu1 = S1 * invn, rs1 = rsqrtf(SS1 * invn - mu1 * mu1 + 1e-5f);

  // normalize + gamma/beta (+ residual li==0); write Y bf16 into panel (qkv lB layout)
  int posrow = tb * 260 + tp * 130;
  unsigned short* ypan = sB;
  const float* pg  = Pg  + (size_t)li * 4160;
  const float* pbe = Pbe + (size_t)li * 4160;
#pragma unroll
  for (int nf = 0; nf < 9; ++nf) {
    int col = nf * 16 + fr;
    if (col >= 130) continue;
    int half = (col >= 65) ? 1 : 0;
    int f5 = col - half * 65;
    float mu = half ? mu1 : mu0, rs = half ? rs1 : rs0;
    float vv[4];
#pragma unroll
    for (int j = 0; j < 4; ++j) {
      int oc = rbase + j;
      float v = (acc[nf][j] - mu) * rs * pg[oc * 65 + f5] + pbe[oc * 65 + f5];
      if (li == 0) v += X[(size_t)(b * 64 + oc) * 52000 + posrow + col];
      vv[j] = v;
    }
    uint2 u;
    u.x = (unsigned)f2bf(vv[0]) | ((unsigned)f2bf(vv[1]) << 16);
    u.y = (unsigned)f2bf(vv[2]) | ((unsigned)f2bf(vv[3]) << 16);
    int idx = col * 64 + (((rbase & ~7)) ^ ((col & 7) << 3)) + (rbase & 7);
    *(uint2*)&ypan[idx] = u;
  }
  __syncthreads();                             // B2: Y panels ready

  // phase-2 MFMA: QKV(lq) = W @ Y^T
  f32x4 acc2[2][9];
#pragma unroll
  for (int i = 0; i < 2; ++i)
#pragma unroll
    for (int j = 0; j < 9; ++j) acc2[i][j] = {0.f, 0.f, 0.f, 0.f};
#pragma unroll
  for (int kk = 0; kk < 2; ++kk) {
    int ko = (kk * 32 + fk * 8) ^ swz;
    short8 a0 = *(const short8*)&lA2[(ws * 32 + fr) * 64 + ko];
    short8 a1 = *(const short8*)&lA2[(ws * 32 + 16 + fr) * 64 + ko];
#pragma unroll
    for (int nf = 0; nf < 9; ++nf) {
      short8 bfr = *(const short8*)&ypan[(nf * 16 + fr) * 64 + ko];
      acc2[0][nf] = __builtin_amdgcn_mfma_f32_16x16x32_bf16(a0, bfr, acc2[0][nf], 0, 0, 0);
      acc2[1][nf] = __builtin_amdgcn_mfma_f32_16x16x32_bf16(a1, bfr, acc2[1][nf], 0, 0, 0);
    }
  }
  __syncthreads();                             // B3: panels + lA2 dead

  // stage gamma/beta table (layer lq) into lds[0..16896)
  for (int it = 0; it < 17; ++it) {
    int i = it * 512 + tid;
    if (i < 8320) {
      int row = i / 65;
      float g, be;
      if (i < 2080)      { g = Qg[lq * 2080 + i];          be = Qbe[lq * 2080 + i]; }
      else if (i < 4160) { g = Kg[lq * 2080 + (i - 2080)]; be = Kbe[lq * 2080 + (i - 2080)]; }
      else               { g = Vg[lq * 4160 + (i - 4160)]; be = Vbe[lq * 4160 + (i - 4160)]; }
      unsigned pk = (unsigned)f2bf(g) | ((unsigned)f2bf(be) << 16);
      *(unsigned*)&lds[(i + row) * 2] = pk;
    }
  }

  // bias + PReLU + group stats in registers (layer lq)
  int r4 = (lane >> 4) * 4;
  int t0 = tb * 4 + tp * 2;
  float mu0_[2], rs0_[2], mu1_[2], rs1_[2];
#pragma unroll
  for (int mf2 = 0; mf2 < 2; ++mf2) {
    int rb = ws * 32 + mf2 * 16 + r4;
    float bias2[4], alpha2;
    if (rb < 32) {
      alpha2 = Qa[lq * 4 + (rb >> 3)];
#pragma unroll
      for (int j = 0; j < 4; ++j) bias2[j] = Qb[lq * 32 + rb + j];
    } else if (rb < 64) {
      alpha2 = Ka[lq * 4 + ((rb - 32) >> 3)];
#pragma unroll
      for (int j = 0; j < 4; ++j) bias2[j] = Kbi[lq * 32 + rb - 32 + j];
    } else {
      alpha2 = Va[lq * 4 + ((rb - 64) >> 4)];
#pragma unroll
      for (int j = 0; j < 4; ++j) bias2[j] = Vb[lq * 64 + rb - 64 + j];
    }
    float t_s0 = 0.f, t_ss0 = 0.f, t_s1 = 0.f, t_ss1 = 0.f;
#pragma unroll
    for (int nf = 0; nf < 9; ++nf) {
      int col = nf * 16 + fr;
#pragma unroll
      for (int j = 0; j < 4; ++j) {
        float v = acc2[mf2][nf][j] + bias2[j];
        v = v >= 0.f ? v : alpha2 * v;
        acc2[mf2][nf][j] = v;
        if (col < 65) { t_s0 += v; t_ss0 += v * v; }
        else if (col < 130) { t_s1 += v; t_ss1 += v * v; }
      }
    }
    if (ws < 2) {
#pragma unroll
      for (int off = 1; off < 32; off <<= 1) {
        t_s0 += __shfl_xor(t_s0, off); t_ss0 += __shfl_xor(t_ss0, off);
        t_s1 += __shfl_xor(t_s1, off); t_ss1 += __shfl_xor(t_ss1, off);
      }
    } else {
#pragma unroll
      for (int off = 1; off < 64; off <<= 1) {
        t_s0 += __shfl_xor(t_s0, off); t_ss0 += __shfl_xor(t_ss0, off);
        t_s1 += __shfl_xor(t_s1, off); t_ss1 += __shfl_xor(t_ss1, off);
      }
    }
    float invn2 = (ws < 2) ? (1.f / 520.f) : (1.f / 1040.f);
    float m0v = t_s0 * invn2, m1v = t_s1 * invn2;
    mu0_[mf2] = m0v; rs0_[mf2] = rsqrtf(t_ss0 * invn2 - m0v * m0v + 1e-5f);
    mu1_[mf2] = m1v; rs1_[mf2] = rsqrtf(t_ss1 * invn2 - m1v * m1v + 1e-5f);
  }
  __syncthreads();                             // B4: gamma/beta table ready

  // normalize + write Q/K/V (layer lq) directly from registers
#pragma unroll
  for (int mf2 = 0; mf2 < 2; ++mf2) {
#pragma unroll
    for (int j = 0; j < 4; ++j) {
      int row = ws * 32 + mf2 * 16 + r4 + j;
      unsigned short* dst; int LD;
      if (row < 32) {
        dst = Qo + ((size_t)((row >> 3) * 4 + b) * 896 + t0) * 576 + (row & 7) * 65; LD = 576;
      } else if (row < 64) {
        int rk = row - 32;
        dst = Ko + ((size_t)((rk >> 3) * 4 + b) * 896 + t0) * 576 + (rk & 7) * 65; LD = 576;
      } else {
        int rv = row - 64;
        dst = Vo + ((size_t)((rv >> 4) * 4 + b) * 800 + t0) * 1040 + (rv & 15) * 65; LD = 1040;
      }
      int grow = row * 132;
#pragma unroll
      for (int nf = 0; nf < 9; ++nf) {
        int col = nf * 16 + fr;
        if (col >= 130) continue;
        int half = (col >= 65) ? 1 : 0;
        int f = col - half * 65;
        unsigned pk = *(const unsigned*)&lds[grow + f * 2];
        float g = bf2f((unsigned short)(pk & 0xffff));
        float be = bf2f((unsigned short)(pk >> 16));
        float mu = half ? mu1_[mf2] : mu0_[mf2];
        float rs = half ? rs1_[mf2] : rs0_[mf2];
        dst[(size_t)half * LD + f] = f2bf((acc2[mf2][nf][j] - mu) * rs * g + be);
      }
    }
  }
}

// ---------------- K5b: final-layer P-proj (li=3) ----------------
__global__ __launch_bounds__(512) void pproj3_kernel(
    const unsigned short* __restrict__ Ot,
    const float* __restrict__ Pw, const float* __restrict__ Pb,
    const float* __restrict__ Pa, const float* __restrict__ Pg, const float* __restrict__ Pbe,
    float* __restrict__ out, int li)
{
  __shared__ __align__(16) float smem[16768];
  __shared__ float redbuf[8][4];
  unsigned short* sA = (unsigned short*)smem;

  int wg = (blockIdx.x & 7) * 100 + (blockIdx.x >> 3);
  int b = wg & 3, tb = wg >> 2;
  int tid = threadIdx.x, lane = tid & 63, wid = tid >> 6;
  int tp = wid >> 2;
  int ws = wid & 3;
  unsigned short* sB = sA + 4096 + tp * 9216;

  const float* pw = Pw + (size_t)li * 4096;
  {
    int row = tid >> 3, c8 = tid & 7;
    float4 f0 = *(const float4*)(pw + row * 64 + c8 * 8);
    float4 f1 = *(const float4*)(pw + row * 64 + c8 * 8 + 4);
    uint4 u;
    u.x = (unsigned)f2bf(f0.x) | ((unsigned)f2bf(f0.y) << 16);
    u.y = (unsigned)f2bf(f0.z) | ((unsigned)f2bf(f0.w) << 16);
    u.z = (unsigned)f2bf(f1.x) | ((unsigned)f2bf(f1.y) << 16);
    u.w = (unsigned)f2bf(f1.z) | ((unsigned)f2bf(f1.w) << 16);
    *(uint4*)&sA[row * 64 + ((c8 * 8) ^ ((row & 7) << 3))] = u;
  }
  const unsigned short* ob = Ot + (size_t)b * 4 * OT_SLAB;
#pragma unroll
  for (int q = 0; q < 5; ++q) {
    int chunk = q * 512 + tid;
    if (chunk < 2304) {
      int pair = (chunk >= 1152) ? 1 : 0;
      int ch = chunk - pair * 1152;
      int row = ch >> 3, c8 = ch & 7;
      int half = (row >= 65) ? 1 : 0;
      int f = row - half * 65;
      int tt = tb * 4 + pair * 2 + half;
      uint4 u = *(const uint4*)&ob[(size_t)(c8 >> 1) * OT_SLAB +
                                   ((size_t)tt * 65 + f) * 16 + (c8 & 1) * 8];
      unsigned short* sbp = sA + 4096 + pair * 9216;
      *(uint4*)&sbp[row * 64 + ((c8 * 8) ^ ((row & 7) << 3))] = u;
    }
  }
  __syncthreads();

  f32x4 acc[9];
#pragma unroll
  for (int j = 0; j < 9; ++j) acc[j] = {0.f, 0.f, 0.f, 0.f};
  const int fr = lane & 15, fk = lane >> 4;
  const int swz = (lane & 7) << 3;
#pragma unroll
  for (int kk = 0; kk < 2; ++kk) {
    int ko = (kk * 32 + fk * 8) ^ swz;
    short8 a = *(const short8*)&sA[(ws * 16 + fr) * 64 + ko];
#pragma unroll
    for (int nf = 0; nf < 9; ++nf) {
      short8 bb2 = *(const short8*)&sB[(nf * 16 + fr) * 64 + ko];
      acc[nf] = __builtin_amdgcn_mfma_f32_16x16x32_bf16(a, bb2, acc[nf], 0, 0, 0);
    }
  }

  float alpha = Pa[li];
  int rbase = ws * 16 + (lane >> 4) * 4;
  float bias[4];
#pragma unroll
  for (int j = 0; j < 4; ++j) bias[j] = Pb[li * 64 + rbase + j];
  float s0 = 0.f, ss0 = 0.f, s1 = 0.f, ss1 = 0.f;
#pragma unroll
  for (int nf = 0; nf < 9; ++nf) {
    int col = nf * 16 + fr;
#pragma unroll
    for (int j = 0; j < 4; ++j) {
      float v = acc[nf][j] + bias[j];
      v = v >= 0.f ? v : alpha * v;
      acc[nf][j] = v;
      if (col < 65) { s0 += v; ss0 += v * v; }
      else if (col < 130) { s1 += v; ss1 += v * v; }
    }
  }
#pragma unroll
  for (int off = 32; off; off >>= 1) {
    s0 += __shfl_xor(s0, off); ss0 += __shfl_xor(ss0, off);
    s1 += __shfl_xor(s1, off); ss1 += __shfl_xor(ss1, off);
  }
  if (lane == 0) {
    redbuf[wid][0] = s0; redbuf[wid][1] = ss0;
    redbuf[wid][2] = s1; redbuf[wid][3] = ss1;
  }
  __syncthreads();
  int rb0 = tp * 4;
  float S0 = redbuf[rb0][0] + redbuf[rb0+1][0] + redbuf[rb0+2][0] + redbuf[rb0+3][0];
  float SS0 = redbuf[rb0][1] + redbuf[rb0+1][1] + redbuf[rb0+2][1] + redbuf[rb0+3][1];
  float S1 = redbuf[rb0][2] + redbuf[rb0+1][2] + redbuf[rb0+2][2] + redbuf[rb0+3][2];
  float SS1 = redbuf[rb0][3] + redbuf[rb0+1][3] + redbuf[rb0+2][3] + redbuf[rb0+3][3];
  const float invn = 1.f / 4160.f;
  float mu0 = S0 * invn, rs0 = rsqrtf(SS0 * invn - mu0 * mu0 + 1e-5f);
  float mu1 = S1 * invn, rs1 = rsqrtf(SS1 * invn - mu1 * mu1 + 1e-5f);

  float* Yfp = smem + tp * 8384;
  const float* pg  = Pg  + (size_t)li * 4160;
  const float* pbe = Pbe + (size_t)li * 4160;
#pragma unroll
  for (int nf = 0; nf < 9; ++nf) {
    int col = nf * 16 + fr;
    if (col >= 130) continue;
    int half = (col >= 65) ? 1 : 0;
    int f5 = col - half * 65;
    float mu = half ? mu1 : mu0, rs = half ? rs1 : rs0;
#pragma unroll
    for (int j = 0; j < 4; ++j) {
      int oc = rbase + j;
      Yfp[oc * 131 + col] = (acc[nf][j] - mu) * rs * pg[oc * 65 + f5] + pbe[oc * 65 + f5];
    }
  }
  __syncthreads();

  int pair = (tid >= 130) ? 1 : 0;
  int pp = tid - pair * 130;
  for (int oc = 0; oc < 64; ++oc) {
    if (tid < 260)
      out[(size_t)(b * 64 + oc) * 52000 + tb * 260 + tid] =
          smem[pair * 8384 + oc * 131 + pp];
  }
}

extern "C" void kernel_launch(void* const* d_in, const int* in_sizes, int n_in,
                              void* d_out, int out_size, void* d_ws, size_t ws_size,
                              hipStream_t stream) {
  const float* pos = (const float*)d_in[0];
  const float* neg = (const float*)d_in[1];
  const float* seg = (const float*)d_in[2];
  const float* Qw  = (const float*)d_in[3];
  const float* Qb  = (const float*)d_in[4];
  const float* Qa  = (const float*)d_in[5];
  const float* Qg  = (const float*)d_in[6];
  const float* Qbe = (const float*)d_in[7];
  const float* Kw  = (const float*)d_in[8];
  const float* Kbi = (const float*)d_in[9];
  const float* Ka  = (const float*)d_in[10];
  const float* Kg  = (const float*)d_in[11];
  const float* Kbe = (const float*)d_in[12];
  const float* Vw  = (const float*)d_in[13];
  const float* Vb  = (const float*)d_in[14];
  const float* Va  = (const float*)d_in[15];
  const float* Vg  = (const float*)d_in[16];
  const float* Vbe = (const float*)d_in[17];
  const float* Pw  = (const float*)d_in[18];
  const float* Pb  = (const float*)d_in[19];
  const float* Pa  = (const float*)d_in[20];
  const float* Pg  = (const float*)d_in[21];
  const float* Pbe = (const float*)d_in[22];
  float* out = (float*)d_out;
  char* base = (char*)d_ws;

  // layout (bytes):
  // X   fp32 [0, 53,248,000)                  (alive all layers: li=0 residual)
  // Xt  bf16 [53,248,000, 79,888,384)         dead after layer-0 qkv;
  //     Ot   [53,248,000, 79,872,000)         4 x 4 x 800 x 65 x 16 (aliases dead Xt)
  // SP  bf16 [79,888,384, 103,743,488)
  // Vt  bf16 [103,743,488, 134,414,336)
  // V   bf16 [134,414,336, 161,038,336)
  // Qb  bf16 [161,038,336, 177,553,408)       exclusive (no Ot aliasing)
  // Kb  bf16 [177,553,408, 194,068,480)       exclusive
  float* X = (float*)base;
  unsigned short* Xt16 = (unsigned short*)(base + 53248000);
  unsigned short* Ot16 = (unsigned short*)(base + 53248000);
  unsigned short* SP16 = (unsigned short*)(base + 79888384);
  unsigned short* Vt16 = (unsigned short*)(base + 103743488);
  unsigned short* V16  = (unsigned short*)(base + 134414336);
  unsigned short* Qb16 = (unsigned short*)(base + 161038336);
  unsigned short* Kb16 = (unsigned short*)(base + 177553408);

  dim3 blk(256);
  const size_t XN = (size_t)BB * CC * TT * FF;
  buildx_kernel<<<(unsigned)((XN + 255) / 256), blk, 0, stream>>>(pos, neg, seg, X);
  xt0_kernel<<<dim3(813, 4), blk, 0, stream>>>(X, Xt16);
  qkv_gemm_kernel<<<800, dim3(512), 0, stream>>>(Xt16, Qw, Qb, Qa, Qg, Qbe,
                                                 Kw, Kbi, Ka, Kg, Kbe,
                                                 Vw, Vb, Va, Vg, Vbe,
                                                 Qb16, Kb16, V16, 0);
  for (int li = 0; li < 4; ++li) {
    vtrans_kernel<<<dim3(13, 17, 16), blk, 0, stream>>>(V16, Vt16);
    qk_mfma_kernel<<<784, blk, 0, stream>>>(Qb16, Kb16, SP16);
    softmax_bf16_kernel<<<3200, blk, 0, stream>>>(SP16);
    pv_mfma_kernel<<<1008, blk, 0, stream>>>(SP16, Vt16, Ot16);
    if (li < 3) {
      fused_pproj_qkv_kernel<<<800, dim3(512), 0, stream>>>(
          Ot16, Pw, Pb, Pa, Pg, Pbe, X,
          Qw, Qb, Qa, Qg, Qbe, Kw, Kbi, Ka, Kg, Kbe, Vw, Vb, Va, Vg, Vbe,
          Qb16, Kb16, V16, li);
    } else {
      pproj3_kernel<<<800, dim3(512), 0, stream>>>(Ot16, Pw, Pb, Pa, Pg, Pbe, out, 3);
    }
  }
}

// Round 15
// 703.579 us; speedup vs baseline: 1.1040x; 1.1040x over previous
//
#include <hip/hip_runtime.h>

#define BB 4
#define CC 64
#define TT 800
#define FF 65
#define EE 8
#define CVV 16
#define HH 4

typedef __attribute__((ext_vector_type(8))) short short8;
typedef __attribute__((ext_vector_type(4))) float f32x4;

#define OT_SLAB (800 * 68 * 16)   // shorts per (b,h) slab of Ot

__device__ __forceinline__ float bf2f(unsigned short u) {
  unsigned v = ((unsigned)u) << 16;
  return __builtin_bit_cast(float, v);
}
__device__ __forceinline__ unsigned short f2bf(float f) {
  unsigned u = __builtin_bit_cast(unsigned, f);
  unsigned r = (u + 0x7fffu + ((u >> 16) & 1u)) >> 16;
  return (unsigned short)r;
}

// direct global->LDS async copy, 16B per lane; lds dst must be wave-uniform
__device__ __forceinline__ void gll16(const void* g, void* l) {
  __builtin_amdgcn_global_load_lds(
      (const __attribute__((address_space(1))) void*)g,
      (__attribute__((address_space(3))) void*)l, 16, 0, 0);
}

// ---------------- K0: x = concat(pos, neg) + seg -> X fp32 ----------------
__global__ __launch_bounds__(256) void buildx_kernel(
    const float* __restrict__ pos, const float* __restrict__ neg,
    const float* __restrict__ seg, float* __restrict__ X)
{
  size_t i = (size_t)blockIdx.x * 256 + threadIdx.x;
  const size_t total = (size_t)BB * CC * TT * FF;
  if (i >= total) return;
  int f = (int)(i % FF);
  size_t r = i / FF;
  int t = (int)(r % TT);
  size_t r2 = r / TT;
  int c = (int)(r2 % CC);
  int b = (int)(r2 / CC);
  float v; int si;
  if (t < 400) { v = pos[(((size_t)b * CC + c) * 400 + t) * FF + f]; si = 0; }
  else         { v = neg[(((size_t)b * CC + c) * 400 + (t - 400)) * FF + f]; si = 1; }
  X[i] = v + seg[(size_t)si * CC * FF + c * FF + f];
}

// ---------------- Xt0: X[b][c][pos] fp32 -> Xt[b][pos][c] bf16 (pos padded 52032) ----------------
__global__ __launch_bounds__(256) void xt0_kernel(
    const float* __restrict__ X, unsigned short* __restrict__ Xt)
{
  __shared__ unsigned short tile[64][66];
  int b = blockIdx.y;
  int p0 = blockIdx.x * 64;
  int tid = threadIdx.x;
#pragma unroll
  for (int it = 0; it < 16; ++it) {
    int idx = it * 256 + tid;
    int c = idx >> 6, pp = idx & 63;
    int ps = p0 + pp;
    float v = (ps < 52000) ? X[((size_t)b * 64 + c) * 52000 + ps] : 0.f;
    tile[pp][c] = f2bf(v);
  }
  __syncthreads();
#pragma unroll
  for (int it = 0; it < 16; ++it) {
    int idx = it * 256 + tid;
    int pp = idx >> 6, c = idx & 63;
    int ps = p0 + pp;
    Xt[((size_t)b * 52032 + ps) * 64 + c] = tile[pp][c];
  }
}

// ---------------- K1: QKV projection, 512 thr, 4 t per block (2 t-pairs) ----------------
__global__ __launch_bounds__(512) void qkv_gemm_kernel(
    const unsigned short* __restrict__ Xt,
    const float* __restrict__ Qw, const float* __restrict__ Qb, const float* __restrict__ Qa,
    const float* __restrict__ Qg, const float* __restrict__ Qbe,
    const float* __restrict__ Kw, const float* __restrict__ Kbi, const float* __restrict__ Ka,
    const float* __restrict__ Kg, const float* __restrict__ Kbe,
    const float* __restrict__ Vw, const float* __restrict__ Vb, const float* __restrict__ Va,
    const float* __restrict__ Vg, const float* __restrict__ Vbe,
    unsigned short* __restrict__ Qo, unsigned short* __restrict__ Ko,
    unsigned short* __restrict__ Vo, int li)
{
  // lA[128][64] | lB0[144][64] | lB1[144][64] = 26624 shorts (53248 B)
  // gamma/beta table (16896 shorts) aliases front after MFMA
  __shared__ __align__(16) unsigned short lds[26624];
  unsigned short* lA = lds;

  int wg = (blockIdx.x & 7) * 100 + (blockIdx.x >> 3);   // 800 = 8*100
  int b = wg & 3, tb = wg >> 2;                          // tb 0..199, covers t 4tb..4tb+3
  int tid = threadIdx.x;
  int lane = tid & 63, wid = tid >> 6;                   // wid 0..7
  int tp = wid >> 2;                                     // t-pair 0/1
  int ws2 = wid & 3;                                     // row-split wave 0..3
  int t0 = tb * 4 + tp * 2;
  unsigned short* lB = lds + 8192 + tp * 9216;

  // re-zero K-dim pad cols [520,576) of Q/K rows t=4tb..4tb+3, all heads (Ot clobbered them)
  for (int i = tid; i < 896; i += 512) {
    int u = i / 28, c = i - u * 28;          // u: h(4) x arr(2) x t(4)
    int h = u >> 3, arr = (u >> 2) & 1, tt = u & 3;
    unsigned short* bp = arr ? Ko : Qo;
    unsigned* dst = (unsigned*)(bp + ((size_t)(h * 4 + b) * 896 + tb * 4 + tt) * 576) + 260 + c;
    *dst = 0u;
  }

  // stage B (async): Xt rows via global_load_lds, pre-swizzled source
  const unsigned short* xb = Xt + ((size_t)b * 52032 + tb * 260) * 64;
  const int srow = lane >> 3;
  const int gc8s = (lane & 7) ^ srow;
#pragma unroll
  for (int it = 0; it < 5; ++it) {
    int s = it * 8 + wid;                    // 36 slabs of 8 rows (2 pairs x 18)
    if (s < 36) {
      int pair = (s >= 18) ? 1 : 0;
      int r0 = (s - pair * 18) * 8;
      int row = r0 + srow;
      gll16(&xb[(size_t)(pair * 130 + row) * 64 + gc8s * 8],
            lds + 8192 + pair * 9216 + r0 * 64);
    }
  }

  // stage A: weights fp32 -> bf16 (rows 0-31 Q, 32-63 K, 64-127 V)
  const float* Wq = Qw + (size_t)li * 2048;
  const float* Wk = Kw + (size_t)li * 2048;
  const float* Wv = Vw + (size_t)li * 4096;
#pragma unroll
  for (int q = 0; q < 2; ++q) {
    int chunk = q * 512 + tid;               // 0..1023
    int row = chunk >> 3, c8 = chunk & 7;
    const float* src = (row < 32) ? (Wq + row * 64)
                     : (row < 64) ? (Wk + (row - 32) * 64)
                                  : (Wv + (row - 64) * 64);
    float4 f0 = *(const float4*)(src + c8 * 8);
    float4 f1 = *(const float4*)(src + c8 * 8 + 4);
    uint4 u;
    u.x = (unsigned)f2bf(f0.x) | ((unsigned)f2bf(f0.y) << 16);
    u.y = (unsigned)f2bf(f0.z) | ((unsigned)f2bf(f0.w) << 16);
    u.z = (unsigned)f2bf(f1.x) | ((unsigned)f2bf(f1.y) << 16);
    u.w = (unsigned)f2bf(f1.z) | ((unsigned)f2bf(f1.w) << 16);
    *(uint4*)&lA[row * 64 + ((c8 * 8) ^ ((row & 7) << 3))] = u;
  }
  __syncthreads();

  // MFMA: wave (tp,ws2) owns rows [ws2*32,+32) x its t-pair's 144 cols
  f32x4 acc[2][9];
#pragma unroll
  for (int i = 0; i < 2; ++i)
#pragma unroll
    for (int j = 0; j < 9; ++j) acc[i][j] = {0.f, 0.f, 0.f, 0.f};
  const int fr = lane & 15, fk = lane >> 4;
  const int swz = (lane & 7) << 3;
#pragma unroll
  for (int kk = 0; kk < 2; ++kk) {
    int ko = (kk * 32 + fk * 8) ^ swz;
    short8 a0 = *(const short8*)&lA[(ws2 * 32 + fr) * 64 + ko];
    short8 a1 = *(const short8*)&lA[(ws2 * 32 + 16 + fr) * 64 + ko];
#pragma unroll
    for (int nf = 0; nf < 9; ++nf) {
      short8 bfr = *(const short8*)&lB[(nf * 16 + fr) * 64 + ko];
      acc[0][nf] = __builtin_amdgcn_mfma_f32_16x16x32_bf16(a0, bfr, acc[0][nf], 0, 0, 0);
      acc[1][nf] = __builtin_amdgcn_mfma_f32_16x16x32_bf16(a1, bfr, acc[1][nf], 0, 0, 0);
    }
  }
  __syncthreads();   // staging dead

  // stage gamma/beta interleaved bf16: lds[(row*66+f)*2] = {g, be}
  for (int it = 0; it < 17; ++it) {
    int i = it * 512 + tid;
    if (i < 8320) {
      int row = i / 65;
      float g, be;
      if (i < 2080)      { g = Qg[li * 2080 + i];          be = Qbe[li * 2080 + i]; }
      else if (i < 4160) { g = Kg[li * 2080 + (i - 2080)]; be = Kbe[li * 2080 + (i - 2080)]; }
      else               { g = Vg[li * 4160 + (i - 4160)]; be = Vbe[li * 4160 + (i - 4160)]; }
      unsigned pk = (unsigned)f2bf(g) | ((unsigned)f2bf(be) << 16);
      *(unsigned*)&lds[(i + row) * 2] = pk;
    }
  }

  // bias + PReLU + group stats fully in registers.
  int r4 = (lane >> 4) * 4;
  float mu0_[2], rs0_[2], mu1_[2], rs1_[2];
#pragma unroll
  for (int mf2 = 0; mf2 < 2; ++mf2) {
    int rbase = ws2 * 32 + mf2 * 16 + r4;
    float bias[4], alpha;
    if (rbase < 32) {
      alpha = Qa[li * 4 + (rbase >> 3)];
#pragma unroll
      for (int j = 0; j < 4; ++j) bias[j] = Qb[li * 32 + rbase + j];
    } else if (rbase < 64) {
      alpha = Ka[li * 4 + ((rbase - 32) >> 3)];
#pragma unroll
      for (int j = 0; j < 4; ++j) bias[j] = Kbi[li * 32 + rbase - 32 + j];
    } else {
      alpha = Va[li * 4 + ((rbase - 64) >> 4)];
#pragma unroll
      for (int j = 0; j < 4; ++j) bias[j] = Vb[li * 64 + rbase - 64 + j];
    }
    float s0 = 0.f, ss0 = 0.f, s1 = 0.f, ss1 = 0.f;
#pragma unroll
    for (int nf = 0; nf < 9; ++nf) {
      int col = nf * 16 + fr;
#pragma unroll
      for (int j = 0; j < 4; ++j) {
        float v = acc[mf2][nf][j] + bias[j];
        v = v >= 0.f ? v : alpha * v;
        acc[mf2][nf][j] = v;
        if (col < 65) { s0 += v; ss0 += v * v; }
        else if (col < 130) { s1 += v; ss1 += v * v; }
      }
    }
    if (ws2 < 2) {
#pragma unroll
      for (int off = 1; off < 32; off <<= 1) {
        s0 += __shfl_xor(s0, off); ss0 += __shfl_xor(ss0, off);
        s1 += __shfl_xor(s1, off); ss1 += __shfl_xor(ss1, off);
      }
    } else {
#pragma unroll
      for (int off = 1; off < 64; off <<= 1) {
        s0 += __shfl_xor(s0, off); ss0 += __shfl_xor(ss0, off);
        s1 += __shfl_xor(s1, off); ss1 += __shfl_xor(ss1, off);
      }
    }
    float invn = (ws2 < 2) ? (1.f / 520.f) : (1.f / 1040.f);
    float m0v = s0 * invn, m1v = s1 * invn;
    mu0_[mf2] = m0v; rs0_[mf2] = rsqrtf(ss0 * invn - m0v * m0v + 1e-5f);
    mu1_[mf2] = m1v; rs1_[mf2] = rsqrtf(ss1 * invn - m1v * m1v + 1e-5f);
  }
  __syncthreads();   // tables ready

  // normalize + write directly from registers
#pragma unroll
  for (int mf2 = 0; mf2 < 2; ++mf2) {
#pragma unroll
    for (int j = 0; j < 4; ++j) {
      int row = ws2 * 32 + mf2 * 16 + r4 + j;
      unsigned short* dst; int LD;
      if (row < 32) {
        dst = Qo + ((size_t)((row >> 3) * 4 + b) * 896 + t0) * 576 + (row & 7) * 65; LD = 576;
      } else if (row < 64) {
        int rk = row - 32;
        dst = Ko + ((size_t)((rk >> 3) * 4 + b) * 896 + t0) * 576 + (rk & 7) * 65; LD = 576;
      } else {
        int rv = row - 64;
        dst = Vo + ((size_t)((rv >> 4) * 4 + b) * 800 + t0) * 1040 + (rv & 15) * 65; LD = 1040;
      }
      int grow = row * 132;
#pragma unroll
      for (int nf = 0; nf < 9; ++nf) {
        int col = nf * 16 + fr;
        if (col >= 130) continue;
        int half = (col >= 65) ? 1 : 0;
        int f = col - half * 65;
        unsigned pk = *(const unsigned*)&lds[grow + f * 2];
        float g = bf2f((unsigned short)(pk & 0xffff));
        float be = bf2f((unsigned short)(pk >> 16));
        float mu = half ? mu1_[mf2] : mu0_[mf2];
        float rs = half ? rs1_[mf2] : rs0_[mf2];
        dst[(size_t)half * LD + f] = f2bf((acc[mf2][nf][j] - mu) * rs * g + be);
      }
    }
  }
}

// ---------------- V transpose: [z][800][cv*65+f] -> Vt [z][n'=f*16+cv][832] ----------------
__global__ __launch_bounds__(256) void vtrans_kernel(
    const unsigned short* __restrict__ V, unsigned short* __restrict__ Vt)
{
  __shared__ unsigned short tile[64][66];
  int z = blockIdx.z;
  const unsigned short* Vp = V + (size_t)z * 800 * 1040;
  unsigned short* Vtp = Vt + (size_t)z * 1152 * 832;
  int t0 = blockIdx.x * 64, n0 = blockIdx.y * 64;
  int tid = threadIdx.x;
#pragma unroll
  for (int it = 0; it < 16; ++it) {
    int idx = it * 256 + tid;
    int r = idx >> 6, c = idx & 63;
    int t = t0 + r, n = n0 + c;
    tile[r][c] = (t < 800 && n < 1040) ? Vp[(size_t)t * 1040 + n] : (unsigned short)0;
  }
  __syncthreads();
#pragma unroll
  for (int it = 0; it < 16; ++it) {
    int idx = it * 256 + tid;
    int r = idx >> 6, c = idx & 63;
    int n = n0 + r;
    if (n < 1040) {
      int cv = n / 65, f5 = n - cv * 65;
      Vtp[(size_t)(f5 * 16 + cv) * 832 + t0 + c] = tile[c][r];
    }
  }
}

// ---------------- shared MFMA GEMM body: C128x128 += A[M,K] * B[N,K]^T ----------------
// global_load_lds staging: lane l stages global chunk (l&7)^(l>>3) of row (l>>3)
// to linear LDS base+l*16 -> identical XOR-swizzled LDS layout.
template <int LDA, int LDB, int KSTEPS>
__device__ __forceinline__ void gemm128(
    const unsigned short* __restrict__ Ag, const unsigned short* __restrict__ Bg,
    int m0, int n0, unsigned short* lA, unsigned short* lB, f32x4 acc[4][4])
{
  const int tid = threadIdx.x;
  const int lane = tid & 63;
  const int wid = tid >> 6;
  const int wm = wid >> 1, wn = wid & 1;

  const int fr = lane & 15, fk = lane >> 4;
  const int swz = (lane & 7) << 3;
  const int srow = lane >> 3;               // 0..7 within 8-row slab
  const int gc8 = (lane & 7) ^ srow;        // pre-swizzled source chunk
  int aoff[4][2], boff[4][2];
#pragma unroll
  for (int mf = 0; mf < 4; ++mf)
#pragma unroll
    for (int kk = 0; kk < 2; ++kk) {
      aoff[mf][kk] = (wm * 64 + mf * 16 + fr) * 64 + ((kk * 32 + fk * 8) ^ swz);
      boff[mf][kk] = (wn * 64 + mf * 16 + fr) * 64 + ((kk * 32 + fk * 8) ^ swz);
    }

  const unsigned short* gA = Ag + (size_t)m0 * LDA;
  const unsigned short* gB = Bg + (size_t)n0 * LDB;

  for (int ks = 0; ks < KSTEPS; ++ks) {
    int k0 = ks * 64;
    __syncthreads();   // previous tile's LDS reads complete
#pragma unroll
    for (int i = 0; i < 4; ++i) {
      int r0 = wid * 32 + i * 8;             // 8-row slab; r0 % 8 == 0
      gll16(&gA[(size_t)(r0 + srow) * LDA + k0 + gc8 * 8], &lA[r0 * 64]);
      gll16(&gB[(size_t)(r0 + srow) * LDB + k0 + gc8 * 8], &lB[r0 * 64]);
    }
    __syncthreads();   // vmcnt drained at barrier -> LDS tile ready
#pragma unroll
    for (int kk = 0; kk < 2; ++kk) {
      short8 a[4], b[4];
#pragma unroll
      for (int i = 0; i < 4; ++i) {
        a[i] = *(const short8*)&lA[aoff[i][kk]];
        b[i] = *(const short8*)&lB[boff[i][kk]];
      }
#pragma unroll
      for (int i = 0; i < 4; ++i)
#pragma unroll
        for (int j = 0; j < 4; ++j)
          acc[i][j] = __builtin_amdgcn_mfma_f32_16x16x32_bf16(a[i], b[j], acc[i][j], 0, 0, 0);
    }
  }
}

// ---------------- K2: S = Q @ K^T * scale -> bf16 scores ----------------
__global__ __launch_bounds__(256) void qk_mfma_kernel(
    const unsigned short* __restrict__ Q, const unsigned short* __restrict__ K,
    unsigned short* __restrict__ SP)
{
  __shared__ __align__(16) unsigned short lA[128 * 64];
  __shared__ __align__(16) unsigned short lB[128 * 64];
  int wg = (blockIdx.x & 7) * 98 + (blockIdx.x >> 3);
  int z = wg / 49, r = wg % 49;
  int nt = r / 7, mt = r % 7;
  const unsigned short* Ag = Q + (size_t)z * 896 * 576;
  const unsigned short* Bg = K + (size_t)z * 896 * 576;
  int m0 = mt * 128, n0 = nt * 128;
  f32x4 acc[4][4];
#pragma unroll
  for (int i = 0; i < 4; ++i)
#pragma unroll
    for (int j = 0; j < 4; ++j) acc[i][j] = {0.f, 0.f, 0.f, 0.f};
  gemm128<576, 576, 9>(Ag, Bg, m0, n0, lA, lB, acc);
  const int lane = threadIdx.x & 63, wid = threadIdx.x >> 6;
  const int wm = wid >> 1, wn = wid & 1;
  unsigned short* Sp = SP + (size_t)z * 896 * 832;
  const float scale = 0.04385290096535146f;   // 1/sqrt(520)
#pragma unroll
  for (int mf = 0; mf < 4; ++mf)
#pragma unroll
    for (int nf = 0; nf < 4; ++nf) {
      int n = n0 + wn * 64 + nf * 16 + (lane & 15);
      if (n >= 800) continue;
#pragma unroll
      for (int j = 0; j < 4; ++j) {
        int m = m0 + wm * 64 + mf * 16 + (lane >> 4) * 4 + j;
        if (m < 800) Sp[(size_t)m * 832 + n] = f2bf(acc[mf][nf][j] * scale);
      }
    }
}

// ---------------- K3: row softmax, one row per wave ----------------
__global__ __launch_bounds__(256) void softmax_bf16_kernel(unsigned short* __restrict__ SP)
{
  int wid = threadIdx.x >> 6, lane = threadIdx.x & 63;
  int row = blockIdx.x * 4 + wid;          // 12800 rows
  int z = row / 800, r = row - z * 800;
  unsigned short* p = SP + (size_t)z * 896 * 832 + (size_t)r * 832;
  float v[13];
  float mx = -1e30f;
#pragma unroll
  for (int i = 0; i < 13; ++i) {
    int col = i * 64 + lane;
    float x = (col < 800) ? bf2f(p[col]) : -1e30f;
    v[i] = x;
    mx = fmaxf(mx, x);
  }
#pragma unroll
  for (int off = 32; off; off >>= 1) mx = fmaxf(mx, __shfl_xor(mx, off));
  float s = 0.f;
#pragma unroll
  for (int i = 0; i < 13; ++i) { v[i] = __expf(v[i] - mx); s += v[i]; }
#pragma unroll
  for (int off = 32; off; off >>= 1) s += __shfl_xor(s, off);
  float inv = 1.0f / s;
#pragma unroll
  for (int i = 0; i < 13; ++i) {
    int col = i * 64 + lane;
    if (col < 832) p[col] = f2bf(v[i] * inv);
  }
}

// ---------------- K4: O = P @ Vt^T -> Ot[b][h][t][f(pad 68)][cv] bf16 ----------------
__global__ __launch_bounds__(256) void pv_mfma_kernel(
    const unsigned short* __restrict__ SP, const unsigned short* __restrict__ Vt,
    unsigned short* __restrict__ Ot)
{
  __shared__ __align__(16) unsigned short lA[128 * 64];
  __shared__ __align__(16) unsigned short lB[128 * 64];
  int wg = (blockIdx.x & 7) * 126 + (blockIdx.x >> 3);
  int z = wg / 63, r = wg % 63;
  int nt = r / 7, mt = r % 7;
  const unsigned short* Ag = SP + (size_t)z * 896 * 832;
  const unsigned short* Bg = Vt + (size_t)z * 1152 * 832;
  int m0 = mt * 128, n0 = nt * 128;
  f32x4 acc[4][4];
#pragma unroll
  for (int i = 0; i < 4; ++i)
#pragma unroll
    for (int j = 0; j < 4; ++j) acc[i][j] = {0.f, 0.f, 0.f, 0.f};
  gemm128<832, 832, 13>(Ag, Bg, m0, n0, lA, lB, acc);
  const int lane = threadIdx.x & 63, wid = threadIdx.x >> 6;
  const int wm = wid >> 1, wn = wid & 1;
  int h = z >> 2, bb = z & 3;
  unsigned short* Op = Ot + (size_t)(bb * 4 + h) * OT_SLAB;
#pragma unroll
  for (int mf = 0; mf < 4; ++mf)
#pragma unroll
    for (int nf = 0; nf < 4; ++nf) {
      int n = n0 + wn * 64 + nf * 16 + (lane & 15);   // n' = f5*16+cv
      if (n >= 1040) continue;
      int f5 = n >> 4, cv = n & 15;
#pragma unroll
      for (int j = 0; j < 4; ++j) {
        int m = m0 + wm * 64 + mf * 16 + (lane >> 4) * 4 + j;
        if (m < 800) Op[((size_t)m * 68 + f5) * 16 + cv] = f2bf(acc[mf][nf][j]);
      }
    }
}

// ---------------- K5: P-proj, 512 thr, 4 t per block (2 t-pairs) ----------------
__global__ __launch_bounds__(512) void pproj_gemm_kernel(
    const unsigned short* __restrict__ Ot,
    const float* __restrict__ Pw, const float* __restrict__ Pb,
    const float* __restrict__ Pa, const float* __restrict__ Pg, const float* __restrict__ Pbe,
    const float* __restrict__ X, float* __restrict__ out,
    unsigned short* __restrict__ Xt, int li)
{
  // staging: sA[64][64] (4096 sh) + sB0/sB1 [144][64] (2x9216 sh) = 45056 B
  // after MFMA: Yf0/Yf1 [64][131] fp32 (2x33536 B = 67072 B) alias the front
  __shared__ __align__(16) float smem[16768];
  __shared__ float redbuf[8][4];
  unsigned short* sA = (unsigned short*)smem;

  int wg = (blockIdx.x & 7) * 100 + (blockIdx.x >> 3);   // 800 = 8*100
  int b = wg & 3, tb = wg >> 2;                          // t = 4tb..4tb+3
  int tid = threadIdx.x, lane = tid & 63, wid = tid >> 6;
  int tp = wid >> 2;                                     // t-pair 0/1
  int ws = wid & 3;                                      // row-split wave
  unsigned short* sB = sA + 4096 + tp * 9216;

  // stage A: Pw fp32 -> bf16 (exactly 512 chunks)
  const float* pw = Pw + (size_t)li * 4096;
  {
    int row = tid >> 3, c8 = tid & 7;
    float4 f0 = *(const float4*)(pw + row * 64 + c8 * 8);
    float4 f1 = *(const float4*)(pw + row * 64 + c8 * 8 + 4);
    uint4 u;
    u.x = (unsigned)f2bf(f0.x) | ((unsigned)f2bf(f0.y) << 16);
    u.y = (unsigned)f2bf(f0.z) | ((unsigned)f2bf(f0.w) << 16);
    u.z = (unsigned)f2bf(f1.x) | ((unsigned)f2bf(f1.y) << 16);
    u.w = (unsigned)f2bf(f1.z) | ((unsigned)f2bf(f1.w) << 16);
    *(uint4*)&sA[row * 64 + ((c8 * 8) ^ ((row & 7) << 3))] = u;
  }
  // stage B both pairs: assemble [row(130 pos)][c=h*16+cv] from Ot [b][h][t][68][16]
  const unsigned short* ob = Ot + (size_t)b * 4 * OT_SLAB;
#pragma unroll
  for (int q = 0; q < 5; ++q) {
    int chunk = q * 512 + tid;
    if (chunk < 2304) {
      int pair = (chunk >= 1152) ? 1 : 0;
      int ch = chunk - pair * 1152;
      int row = ch >> 3, c8 = ch & 7;         // h = c8>>1, cv0 = (c8&1)*8
      int half = (row >= 65) ? 1 : 0;
      int f = row - half * 65;
      int tt = tb * 4 + pair * 2 + half;
      uint4 u = *(const uint4*)&ob[(size_t)(c8 >> 1) * OT_SLAB +
                                   ((size_t)tt * 68 + f) * 16 + (c8 & 1) * 8];
      unsigned short* sbp = sA + 4096 + pair * 9216;
      *(uint4*)&sbp[row * 64 + ((c8 * 8) ^ ((row & 7) << 3))] = u;
    }
  }
  __syncthreads();

  f32x4 acc[9];
#pragma unroll
  for (int j = 0; j < 9; ++j) acc[j] = {0.f, 0.f, 0.f, 0.f};
  const int fr = lane & 15, fk = lane >> 4;
  const int swz = (lane & 7) << 3;
#pragma unroll
  for (int kk = 0; kk < 2; ++kk) {
    int ko = (kk * 32 + fk * 8) ^ swz;
    short8 a = *(const short8*)&sA[(ws * 16 + fr) * 64 + ko];
#pragma unroll
    for (int nf = 0; nf < 9; ++nf) {
      short8 bb2 = *(const short8*)&sB[(nf * 16 + fr) * 64 + ko];
      acc[nf] = __builtin_amdgcn_mfma_f32_16x16x32_bf16(a, bb2, acc[nf], 0, 0, 0);
    }
  }

  // bias + PReLU + group stats (groups: (pair, t-half), 64x65 each)
  float alpha = Pa[li];
  int rbase = ws * 16 + (lane >> 4) * 4;
  float bias[4];
#pragma unroll
  for (int j = 0; j < 4; ++j) bias[j] = Pb[li * 64 + rbase + j];
  float s0 = 0.f, ss0 = 0.f, s1 = 0.f, ss1 = 0.f;
#pragma unroll
  for (int nf = 0; nf < 9; ++nf) {
    int col = nf * 16 + fr;
#pragma unroll
    for (int j = 0; j < 4; ++j) {
      float v = acc[nf][j] + bias[j];
      v = v >= 0.f ? v : alpha * v;
      acc[nf][j] = v;
      if (col < 65) { s0 += v; ss0 += v * v; }
      else if (col < 130) { s1 += v; ss1 += v * v; }
    }
  }
#pragma unroll
  for (int off = 32; off; off >>= 1) {
    s0 += __shfl_xor(s0, off); ss0 += __shfl_xor(ss0, off);
    s1 += __shfl_xor(s1, off); ss1 += __shfl_xor(ss1, off);
  }
  if (lane == 0) {
    redbuf[wid][0] = s0; redbuf[wid][1] = ss0;
    redbuf[wid][2] = s1; redbuf[wid][3] = ss1;
  }
  __syncthreads();   // also: all sA/sB reads complete -> safe to overwrite as Yf
  int rb0 = tp * 4;
  float S0 = redbuf[rb0][0] + redbuf[rb0+1][0] + redbuf[rb0+2][0] + redbuf[rb0+3][0];
  float SS0 = redbuf[rb0][1] + redbuf[rb0+1][1] + redbuf[rb0+2][1] + redbuf[rb0+3][1];
  float S1 = redbuf[rb0][2] + redbuf[rb0+1][2] + redbuf[rb0+2][2] + redbuf[rb0+3][2];
  float SS1 = redbuf[rb0][3] + redbuf[rb0+1][3] + redbuf[rb0+2][3] + redbuf[rb0+3][3];
  const float invn = 1.f / 4160.f;
  float mu0 = S0 * invn, rs0 = rsqrtf(SS0 * invn - mu0 * mu0 + 1e-5f);
  float mu1 = S1 * invn, rs1 = rsqrtf(SS1 * invn - mu1 * mu1 + 1e-5f);

  // normalize + gamma/beta (+ residual li==0), write fp32 to Yf (stride 131)
  float* Yfp = smem + tp * 8384;
  const float* pg  = Pg  + (size_t)li * 4160;
  const float* pbe = Pbe + (size_t)li * 4160;
  int posp = tb * 260 + tp * 130;
#pragma unroll
  for (int nf = 0; nf < 9; ++nf) {
    int col = nf * 16 + fr;
    if (col >= 130) continue;
    int half = (col >= 65) ? 1 : 0;
    int f5 = col - half * 65;
    float mu = half ? mu1 : mu0, rs = half ? rs1 : rs0;
#pragma unroll
    for (int j = 0; j < 4; ++j) {
      int oc = rbase + j;
      float v = (acc[nf][j] - mu) * rs * pg[oc * 65 + f5] + pbe[oc * 65 + f5];
      if (li == 0) v += X[(size_t)(b * 64 + oc) * 52000 + posp + col];
      Yfp[oc * 131 + col] = v;
    }
  }
  __syncthreads();

  if (li < 3) {
    int oc = tid & 63, pq = tid >> 6;        // pq 0..7
#pragma unroll
    for (int it = 0; it < 33; ++it) {
      int p2 = it * 8 + pq;
      if (p2 < 260) {
        int pair = (p2 >= 130) ? 1 : 0;
        int pp = p2 - pair * 130;
        Xt[((size_t)b * 52032 + tb * 260 + p2) * 64 + oc] =
            f2bf(smem[pair * 8384 + oc * 131 + pp]);
      }
    }
  } else {
    int pair = (tid >= 130) ? 1 : 0;
    int pp = tid - pair * 130;
    for (int oc = 0; oc < 64; ++oc) {
      if (tid < 260)
        out[(size_t)(b * 64 + oc) * 52000 + tb * 260 + tid] =
            smem[pair * 8384 + oc * 131 + pp];
    }
  }
}

extern "C" void kernel_launch(void* const* d_in, const int* in_sizes, int n_in,
                              void* d_out, int out_size, void* d_ws, size_t ws_size,
                              hipStream_t stream) {
  const float* pos = (const float*)d_in[0];
  const float* neg = (const float*)d_in[1];
  const float* seg = (const float*)d_in[2];
  const float* Qw  = (const float*)d_in[3];
  const float* Qb  = (const float*)d_in[4];
  const float* Qa  = (const float*)d_in[5];
  const float* Qg  = (const float*)d_in[6];
  const float* Qbe = (const float*)d_in[7];
  const float* Kw  = (const float*)d_in[8];
  const float* Kbi = (const float*)d_in[9];
  const float* Ka  = (const float*)d_in[10];
  const float* Kg  = (const float*)d_in[11];
  const float* Kbe = (const float*)d_in[12];
  const float* Vw  = (const float*)d_in[13];
  const float* Vb  = (const float*)d_in[14];
  const float* Va  = (const float*)d_in[15];
  const float* Vg  = (const float*)d_in[16];
  const float* Vbe = (const float*)d_in[17];
  const float* Pw  = (const float*)d_in[18];
  const float* Pb  = (const float*)d_in[19];
  const float* Pa  = (const float*)d_in[20];
  const float* Pg  = (const float*)d_in[21];
  const float* Pbe = (const float*)d_in[22];
  float* out = (float*)d_out;
  char* base = (char*)d_ws;

  // layout (bytes):
  // X   fp32 [0, 53,248,000)
  // Xt  bf16 [53,248,000, 79,888,384)     4 x 52032 x 64
  // SP  bf16 [79,888,384, 103,743,488)    16 x 896 x 832
  // Vt  bf16 [103,743,488, 134,414,336)   16 x 1152 x 832
  // V   bf16 [134,414,336, 161,038,336)   16 x 800 x 1040
  // Qb  bf16 [161,038,336, 177,553,408)   16 x 896 x 576
  // Kb  bf16 [177,553,408, 194,068,480)   16 x 896 x 576
  // Ot  bf16 [161,038,336, 188,891,136)   4 x 4 x 800 x 68 x 16 (aliases Qb + part of Kb;
  //          safe: dead after qk in stream order; qkv re-zeros K-pads each layer)
  float* X = (float*)base;
  unsigned short* Xt16 = (unsigned short*)(base + 53248000);
  unsigned short* SP16 = (unsigned short*)(base + 79888384);
  unsigned short* Vt16 = (unsigned short*)(base + 103743488);
  unsigned short* V16  = (unsigned short*)(base + 134414336);
  unsigned short* Qb16 = (unsigned short*)(base + 161038336);
  unsigned short* Kb16 = (unsigned short*)(base + 177553408);
  unsigned short* Ot16 = (unsigned short*)(base + 161038336);

  dim3 blk(256);
  const size_t XN = (size_t)BB * CC * TT * FF;
  buildx_kernel<<<(unsigned)((XN + 255) / 256), blk, 0, stream>>>(pos, neg, seg, X);
  xt0_kernel<<<dim3(813, 4), blk, 0, stream>>>(X, Xt16);
  for (int li = 0; li < 4; ++li) {
    qkv_gemm_kernel<<<800, dim3(512), 0, stream>>>(Xt16, Qw, Qb, Qa, Qg, Qbe,
                                                   Kw, Kbi, Ka, Kg, Kbe,
                                                   Vw, Vb, Va, Vg, Vbe,
                                                   Qb16, Kb16, V16, li);
    vtrans_kernel<<<dim3(13, 17, 16), blk, 0, stream>>>(V16, Vt16);
    qk_mfma_kernel<<<784, blk, 0, stream>>>(Qb16, Kb16, SP16);
    softmax_bf16_kernel<<<3200, blk, 0, stream>>>(SP16);
    pv_mfma_kernel<<<1008, blk, 0, stream>>>(SP16, Vt16, Ot16);
    pproj_gemm_kernel<<<800, dim3(512), 0, stream>>>(Ot16, Pw, Pb, Pa, Pg, Pbe,
                                                     X, out, Xt16, li);
  }
}